// Round 5
// baseline (247.391 us; speedup 1.0000x reference)
//
#include <hip/hip_runtime.h>

#define BB 4
#define TT 32
#define DD 256
#define NN 1024

// ws layout (float indices)
#define XN_OFF   0                      // xn [B*T][N]
#define TN_OFF   131072                 // tn [B*T][N]  (tn[b][t] = tgt_neurons[b][t+1])
#define PB_OFF   262144                 // p  [B*T][2][N]
#define RB_OFF   524288                 // r  [B*T][N]
#define FLG_OFF  655360                 // flags [3 stages][4 b][16 wg][32] u32 (one 128B line per flag)
#define FLG_WORDS 6144                  // 3*4*16*32
#define WS_END   (FLG_OFF + FLG_WORDS)

// ---------------- kernel 1: xn = relu(LN(x @ E)), tn shifted; grid = 64 ----------------
__global__ __launch_bounds__(256) void precompute_kernel(
    const float* __restrict__ x_seq, const float* __restrict__ targets,
    const float* __restrict__ E, float* __restrict__ ws)
{
    __shared__ float xr[4][DD];
    __shared__ float redS[4][4], redSS[4][4];
    const int blk = blockIdx.x;        // 0..63
    const int bt0 = blk * 2, bt1 = bt0 + 1;
    const int tid = threadIdx.x;
    const int lane = tid & 63, w = tid >> 6;

    xr[0][tid] = x_seq[(size_t)bt0 * DD + tid];
    xr[1][tid] = x_seq[(size_t)bt1 * DD + tid];
    xr[2][tid] = targets[(size_t)bt0 * DD + tid];
    xr[3][tid] = targets[(size_t)bt1 * DD + tid];
    __syncthreads();

    const float4* E4 = (const float4*)E;
    float4 acc[4];
#pragma unroll
    for (int r = 0; r < 4; ++r) acc[r] = make_float4(0.f, 0.f, 0.f, 0.f);
#pragma unroll 4
    for (int k = 0; k < DD; ++k) {
        float4 e = E4[(size_t)k * (NN / 4) + tid];
#pragma unroll
        for (int r = 0; r < 4; ++r) {
            float xv = xr[r][k];
            acc[r].x += xv * e.x; acc[r].y += xv * e.y;
            acc[r].z += xv * e.z; acc[r].w += xv * e.w;
        }
    }
    float s[4], ss[4];
#pragma unroll
    for (int r = 0; r < 4; ++r) {
        s[r]  = acc[r].x + acc[r].y + acc[r].z + acc[r].w;
        ss[r] = acc[r].x*acc[r].x + acc[r].y*acc[r].y + acc[r].z*acc[r].z + acc[r].w*acc[r].w;
    }
#pragma unroll
    for (int d = 1; d < 64; d <<= 1) {
#pragma unroll
        for (int r = 0; r < 4; ++r) {
            s[r]  += __shfl_xor(s[r], d, 64);
            ss[r] += __shfl_xor(ss[r], d, 64);
        }
    }
    if (lane == 0) {
#pragma unroll
        for (int r = 0; r < 4; ++r) { redS[w][r] = s[r]; redSS[w][r] = ss[r]; }
    }
    __syncthreads();
#pragma unroll
    for (int r = 0; r < 4; ++r) {
        s[r]  = redS[0][r] + redS[1][r] + redS[2][r] + redS[3][r];
        ss[r] = redSS[0][r] + redSS[1][r] + redSS[2][r] + redSS[3][r];
    }
#pragma unroll
    for (int r = 0; r < 4; ++r) {
        const float mu  = s[r] * (1.0f / NN);
        const float var = ss[r] * (1.0f / NN) - mu * mu;
        const float inv = rsqrtf(var + 1e-5f);
        float4 o;
        o.x = fmaxf(0.f, (acc[r].x - mu) * inv);
        o.y = fmaxf(0.f, (acc[r].y - mu) * inv);
        o.z = fmaxf(0.f, (acc[r].z - mu) * inv);
        o.w = fmaxf(0.f, (acc[r].w - mu) * inv);
        const int bt = (r & 1) ? bt1 : bt0;
        float* dst = nullptr;
        if (r < 2) dst = ws + XN_OFF + (size_t)bt * NN;
        else if ((bt & 31) > 0) dst = ws + TN_OFF + (size_t)(bt - 1) * NN;
        if (dst) ((float4*)dst)[tid] = o;
    }
}

// ---------------- kernel 2: 4-role persistent pipeline, 4-step batches ----------------
// Cross-WG data moves through RELAXED AGENT atomics (device-scope, IF$-coherent);
// polls are RELAXED + compiler fence; ONE RELEASE flag store per WG per 4-step batch.
// R0-R4 established: period = fixed_handoff(~5us) + steps*compute(~1.35us), so larger
// batches amortize the handoff. Inputs stay LDS-resident to cap register pressure.
__device__ __forceinline__ float ald(const float* p) {
    return __hip_atomic_load(p, __ATOMIC_RELAXED, __HIP_MEMORY_SCOPE_AGENT);
}
__device__ __forceinline__ unsigned long long ald64(const unsigned long long* p) {
    return __hip_atomic_load(p, __ATOMIC_RELAXED, __HIP_MEMORY_SCOPE_AGENT);
}
__device__ __forceinline__ void ast(float* p, float v) {
    __hip_atomic_store(p, v, __ATOMIC_RELAXED, __HIP_MEMORY_SCOPE_AGENT);
}
__device__ __forceinline__ unsigned aldu_rlx(const unsigned* p) {
    return __hip_atomic_load(p, __ATOMIC_RELAXED, __HIP_MEMORY_SCOPE_AGENT);
}

__global__ __launch_bounds__(512, 1) void mega_kernel(
    const float* __restrict__ Dy, float* __restrict__ out, float* __restrict__ ws)
{
    __shared__ float sh[6144];   // chain: 4 padded p-vectors (1088, stride 1152); out: r[4096]+partial[2048]
    const int blk = blockIdx.x;  // 0..223  (grid <= 256 CUs -> 1 WG/CU, so (512,1) costs no occupancy)
    const int tid = threadIdx.x;

    float* pb     = ws + PB_OFF;
    float* rb     = ws + RB_OFF;
    unsigned* flg = (unsigned*)(ws + FLG_OFF);

    if (blk < 192) {
        // ---- chain stages 0,1,2 ----
        const int stage = blk >> 6;          // 0,1,2
        const int b     = (blk >> 4) & 3;
        const int wg    = blk & 15;
        const int lane  = tid & 63;
        const int w     = tid >> 6;
        const int colbase = wg * 64 + w * 8;   // wave owns cols colbase..+7
        const int row0    = lane * 16;         // lane owns rows row0..+15
        const float* xn = ws + XN_OFF + (size_t)b * TT * NN;
        const float* tn = ws + TN_OFF + (size_t)b * TT * NN;
        unsigned* myflag = flg + ((size_t)(stage * 4 + b) * 16 + wg) * 32;
        const unsigned* inflags =
            (stage > 0) ? flg + ((size_t)((stage - 1) * 4 + b) * 16) * 32 : (const unsigned*)0;
        unsigned seen = 0;   // monotone cache of min producer flag seen by this lane

        float G[16][8];
#pragma unroll
        for (int i = 0; i < 16; ++i)
#pragma unroll
            for (int c = 0; c < 8; ++c)
                G[i][c] = (row0 + i == colbase + c) ? 0.01f : 0.0f;

#pragma unroll 1
        for (int t = 0; t < TT; t += 4) {
            const int bt = b * TT + t;
            float* pbase = pb + (size_t)bt * 2 * NN;   // p1(t+j) = pbase + (2j)*NN, p2(t+j) = +NN

            float v1own[4] = {0.f, 0.f, 0.f, 0.f};

            if (stage != 0) {
                // one RELAXED poll covers all 4 steps: all producers at flag >= t+4
                const unsigned tgt = (unsigned)(t + 4);
                if (tid < 64) {
                    if (seen < tgt) {
                        const unsigned* p = inflags + (size_t)(tid & 15) * 32;
                        int g = 0;
                        for (;;) {
                            unsigned v = aldu_rlx(p);
                            if (v > seen) seen = v;
                            if (__all(seen >= tgt)) break;
                            __builtin_amdgcn_s_sleep(1);
                            if (++g > (1 << 22)) break;  // fail visibly, never hang
                        }
                    }
                }
                __syncthreads();
                asm volatile("" ::: "memory");   // no hoisting of data reads above the poll
                // stage-2 p1 reads for all 4 steps: in flight with the exchange gathers
                if (stage == 2) {
#pragma unroll
                    for (int j = 0; j < 4; ++j)
                        v1own[j] = ald(pbase + (size_t)(2 * j) * NN + colbase + (lane & 7));
                }
                // cooperative exchange of all 4 vectors (independent loads, one latency window)
                union { unsigned long long u; float f[2]; } cv[4];
#pragma unroll
                for (int j = 0; j < 4; ++j) {
                    const float* src = pbase + (size_t)(2 * j) * NN + ((stage == 1) ? 0 : NN);
                    cv[j].u = ald64((const unsigned long long*)src + tid);
                }
                const int e0 = 2 * tid;
#pragma unroll
                for (int j = 0; j < 4; ++j) {
                    sh[j * 1152 + e0 + (e0 >> 4)]     = cv[j].f[0];
                    sh[j * 1152 + e0 + 1 + (e0 >> 4)] = cv[j].f[1];
                }
                __syncthreads();
            }

            // ======== 4 steps: matvec -> store -> G-update (last update deferred) ========
            float xsave[16];   // stage0's j=3 input, kept for the deferred update
#pragma unroll
            for (int j = 0; j < 4; ++j) {
                const int tj = t + j;
                float in[16];
                if (stage == 0) {
                    const float4* xp = (const float4*)(xn + (size_t)tj * NN + row0);
                    float4 q0 = xp[0], q1 = xp[1], q2 = xp[2], q3 = xp[3];
                    in[0]=q0.x; in[1]=q0.y; in[2]=q0.z; in[3]=q0.w;
                    in[4]=q1.x; in[5]=q1.y; in[6]=q1.z; in[7]=q1.w;
                    in[8]=q2.x; in[9]=q2.y; in[10]=q2.z; in[11]=q2.w;
                    in[12]=q3.x; in[13]=q3.y; in[14]=q3.z; in[15]=q3.w;
                    if (j == 3) {
#pragma unroll
                        for (int k = 0; k < 16; ++k) xsave[k] = in[k];
                    }
                } else {
#pragma unroll
                    for (int k = 0; k < 16; ++k) in[k] = sh[j * 1152 + lane * 17 + k];
                }

                float acc[8] = {0.f,0.f,0.f,0.f,0.f,0.f,0.f,0.f};
#pragma unroll
                for (int i = 0; i < 16; ++i)
#pragma unroll
                    for (int c = 0; c < 8; ++c) acc[c] += in[i] * G[i][c];

                // reduce-scatter: lane ends with full sum for col colbase + (lane&7)
                float t4[8];
#pragma unroll
                for (int c = 0; c < 8; ++c) t4[c] = __shfl_xor(acc[c], 4, 64);
                const bool k2 = (lane & 4) != 0;
                float s4[4];
#pragma unroll
                for (int k = 0; k < 4; ++k) s4[k] = k2 ? (acc[4+k] + t4[4+k]) : (acc[k] + t4[k]);
                float t2[4];
#pragma unroll
                for (int k = 0; k < 4; ++k) t2[k] = __shfl_xor(s4[k], 2, 64);
                const bool k1 = (lane & 2) != 0;
                float s2[2];
#pragma unroll
                for (int k = 0; k < 2; ++k) s2[k] = k1 ? (s4[2+k] + t2[2+k]) : (s4[k] + t2[k]);
                float t1[2];
#pragma unroll
                for (int k = 0; k < 2; ++k) t1[k] = __shfl_xor(s2[k], 1, 64);
                float v = (lane & 1) ? (s2[1] + t1[1]) : (s2[0] + t1[0]);
                v += __shfl_xor(v, 8, 64);
                v += __shfl_xor(v, 16, 64);
                v += __shfl_xor(v, 32, 64);

                if (stage == 0) {
                    if (lane < 8) ast(pbase + (size_t)(2 * j) * NN + colbase + lane, v);
                } else if (stage == 1) {
                    if (lane < 8) ast(pbase + (size_t)(2 * j) * NN + NN + colbase + lane, v);
                } else {
                    const int c = colbase + (lane & 7);
                    const float v2own = sh[j * 1152 + c + (c >> 4)];
                    float r = fmaxf(v, fmaxf(v1own[j], v2own));
                    if (lane < 8) ast(rb + (size_t)(bt + j) * NN + colbase + lane, r);
                }

                // inline G update for steps j=0..2 (j=3 deferred past the release)
                if (j < 3) {
                    float x[16];
                    if (stage == 0) {
#pragma unroll
                        for (int k = 0; k < 16; ++k) x[k] = in[k];
                    } else {
                        const float4* xp = (const float4*)(xn + (size_t)tj * NN + row0);
                        float4 q0 = xp[0], q1 = xp[1], q2 = xp[2], q3 = xp[3];
                        x[0]=q0.x; x[1]=q0.y; x[2]=q0.z; x[3]=q0.w;
                        x[4]=q1.x; x[5]=q1.y; x[6]=q1.z; x[7]=q1.w;
                        x[8]=q2.x; x[9]=q2.y; x[10]=q2.z; x[11]=q2.w;
                        x[12]=q3.x; x[13]=q3.y; x[14]=q3.z; x[15]=q3.w;
                    }
                    const float4 ta = *(const float4*)(tn + (size_t)tj * NN + colbase);
                    const float4 tb = *(const float4*)(tn + (size_t)tj * NN + colbase + 4);
                    const float tv[8] = {0.5f*ta.x, 0.5f*ta.y, 0.5f*ta.z, 0.5f*ta.w,
                                         0.5f*tb.x, 0.5f*tb.y, 0.5f*tb.z, 0.5f*tb.w};
#pragma unroll
                    for (int c = 0; c < 8; ++c)
#pragma unroll
                        for (int i = 0; i < 16; ++i)
                            G[i][c] = fmaxf(G[i][c], x[i] * tv[c]);
                }
            }

            __syncthreads();   // one drain for all 4 steps' device-scope stores
            if (tid == 0)      // one RELEASE per batch: publishes steps t..t+3
                __hip_atomic_store(myflag, (unsigned)(t + 4),
                                   __ATOMIC_RELEASE, __HIP_MEMORY_SCOPE_AGENT);

            // deferred G update for step t+3 — after the release, overlaps flag propagation
            if (t + 3 < TT - 1) {
                const int tj = t + 3;
                float x[16];
                if (stage == 0) {
#pragma unroll
                    for (int k = 0; k < 16; ++k) x[k] = xsave[k];
                } else {
                    const float4* xp = (const float4*)(xn + (size_t)tj * NN + row0);
                    float4 q0 = xp[0], q1 = xp[1], q2 = xp[2], q3 = xp[3];
                    x[0]=q0.x; x[1]=q0.y; x[2]=q0.z; x[3]=q0.w;
                    x[4]=q1.x; x[5]=q1.y; x[6]=q1.z; x[7]=q1.w;
                    x[8]=q2.x; x[9]=q2.y; x[10]=q2.z; x[11]=q2.w;
                    x[12]=q3.x; x[13]=q3.y; x[14]=q3.z; x[15]=q3.w;
                }
                const float4 ta = *(const float4*)(tn + (size_t)tj * NN + colbase);
                const float4 tb = *(const float4*)(tn + (size_t)tj * NN + colbase + 4);
                const float tv[8] = {0.5f*ta.x, 0.5f*ta.y, 0.5f*ta.z, 0.5f*ta.w,
                                     0.5f*tb.x, 0.5f*tb.y, 0.5f*tb.z, 0.5f*tb.w};
#pragma unroll
                for (int c = 0; c < 8; ++c)
#pragma unroll
                    for (int i = 0; i < 16; ++i)
                        G[i][c] = fmaxf(G[i][c], x[i] * tv[c]);
            }
        }
    } else {
        // ---- out stage: y = relu(r @ Dy) for 4 consecutive steps, single Dy pass ----
        const int k   = blk - 192;        // 0..31
        const int b   = k >> 3;
        const int t0  = (k & 7) * 4;
        const int bt0 = b * TT + t0;
        // RELAXED poll of the 16 stage-2 flags (monotone batch counts; t0+4 is a batch boundary)
        if (tid < 64) {
            const unsigned* p = flg + ((size_t)(2 * 4 + b) * 16 + (tid & 15)) * 32;
            const unsigned tgt = (unsigned)(t0 + 4);
            int g = 0;
            for (;;) {
                unsigned v = aldu_rlx(p);
                if (__all(v >= tgt)) break;
                __builtin_amdgcn_s_sleep(1);
                if (++g > (1 << 22)) break;
            }
        }
        __syncthreads();
        asm volatile("" ::: "memory");
#pragma unroll
        for (int j = 0; j < 4; ++j) {
            const float* r = rb + (size_t)(bt0 + j) * NN;
            sh[tid * 4 + j]         = ald(r + tid);
            sh[(tid + 512) * 4 + j] = ald(r + tid + 512);
        }
        __syncthreads();
        const int d = tid & 255, h = tid >> 8;
        float acc[4] = {0.f, 0.f, 0.f, 0.f};
        const int n0 = h * 512;
#pragma unroll 8
        for (int n = n0; n < n0 + 512; ++n) {
            const float dv = Dy[(size_t)n * DD + d];
            const float4 rv = *(const float4*)&sh[n * 4];   // wave-uniform n -> LDS broadcast
            acc[0] += rv.x * dv; acc[1] += rv.y * dv;
            acc[2] += rv.z * dv; acc[3] += rv.w * dv;
        }
#pragma unroll
        for (int j = 0; j < 4; ++j) sh[4096 + (h * 4 + j) * 256 + d] = acc[j];
        __syncthreads();
        if (tid < 256) {
#pragma unroll
            for (int j = 0; j < 4; ++j)
                out[(size_t)(bt0 + j) * DD + tid] =
                    fmaxf(0.f, sh[4096 + j * 256 + tid] + sh[4096 + (4 + j) * 256 + tid]);
        }
    }
}

extern "C" void kernel_launch(void* const* d_in, const int* in_sizes, int n_in,
                              void* d_out, int out_size, void* d_ws, size_t ws_size,
                              hipStream_t stream) {
    const float* x_seq   = (const float*)d_in[0];
    const float* targets = (const float*)d_in[1];
    const float* E       = (const float*)d_in[2];
    const float* Dy      = (const float*)d_in[3];
    float* out = (float*)d_out;
    float* ws  = (float*)d_ws;

    // zero the flags (data is flag-protected; flags are monotone batch counts)
    hipMemsetAsync(ws + FLG_OFF, 0, (size_t)FLG_WORDS * sizeof(unsigned), stream);

    precompute_kernel<<<BB * TT / 2, 256, 0, stream>>>(x_seq, targets, E, ws);
    mega_kernel<<<224, 512, 0, stream>>>(Dy, out, ws);
}

// Round 6
// 203.984 us; speedup vs baseline: 1.2128x; 1.2128x over previous
//
#include <hip/hip_runtime.h>

#define BB 4
#define TT 32
#define DD 256
#define NN 1024

// ws layout (float indices)
#define XN_OFF   0                      // xn [B*T][N]
#define TN_OFF   131072                 // tn [B*T][N]  (tn[b][t] = tgt_neurons[b][t+1])
#define PB_OFF   262144                 // p  [B*T][2][N]
#define RB_OFF   524288                 // r  [B*T][N]
#define FLG_OFF  655360                 // flags [3 stages][4 b][16 wg][32] u32 (one 128B line per flag)
#define FLG_WORDS 6144                  // 3*4*16*32
#define WS_END   (FLG_OFF + FLG_WORDS)

// ---------------- kernel 1: xn = relu(LN(x @ E)), tn shifted; grid = 64 ----------------
__global__ __launch_bounds__(256) void precompute_kernel(
    const float* __restrict__ x_seq, const float* __restrict__ targets,
    const float* __restrict__ E, float* __restrict__ ws)
{
    __shared__ float xr[4][DD];
    __shared__ float redS[4][4], redSS[4][4];
    const int blk = blockIdx.x;        // 0..63
    const int bt0 = blk * 2, bt1 = bt0 + 1;
    const int tid = threadIdx.x;
    const int lane = tid & 63, w = tid >> 6;

    xr[0][tid] = x_seq[(size_t)bt0 * DD + tid];
    xr[1][tid] = x_seq[(size_t)bt1 * DD + tid];
    xr[2][tid] = targets[(size_t)bt0 * DD + tid];
    xr[3][tid] = targets[(size_t)bt1 * DD + tid];
    __syncthreads();

    const float4* E4 = (const float4*)E;
    float4 acc[4];
#pragma unroll
    for (int r = 0; r < 4; ++r) acc[r] = make_float4(0.f, 0.f, 0.f, 0.f);
#pragma unroll 4
    for (int k = 0; k < DD; ++k) {
        float4 e = E4[(size_t)k * (NN / 4) + tid];
#pragma unroll
        for (int r = 0; r < 4; ++r) {
            float xv = xr[r][k];
            acc[r].x += xv * e.x; acc[r].y += xv * e.y;
            acc[r].z += xv * e.z; acc[r].w += xv * e.w;
        }
    }
    float s[4], ss[4];
#pragma unroll
    for (int r = 0; r < 4; ++r) {
        s[r]  = acc[r].x + acc[r].y + acc[r].z + acc[r].w;
        ss[r] = acc[r].x*acc[r].x + acc[r].y*acc[r].y + acc[r].z*acc[r].z + acc[r].w*acc[r].w;
    }
#pragma unroll
    for (int d = 1; d < 64; d <<= 1) {
#pragma unroll
        for (int r = 0; r < 4; ++r) {
            s[r]  += __shfl_xor(s[r], d, 64);
            ss[r] += __shfl_xor(ss[r], d, 64);
        }
    }
    if (lane == 0) {
#pragma unroll
        for (int r = 0; r < 4; ++r) { redS[w][r] = s[r]; redSS[w][r] = ss[r]; }
    }
    __syncthreads();
#pragma unroll
    for (int r = 0; r < 4; ++r) {
        s[r]  = redS[0][r] + redS[1][r] + redS[2][r] + redS[3][r];
        ss[r] = redSS[0][r] + redSS[1][r] + redSS[2][r] + redSS[3][r];
    }
#pragma unroll
    for (int r = 0; r < 4; ++r) {
        const float mu  = s[r] * (1.0f / NN);
        const float var = ss[r] * (1.0f / NN) - mu * mu;
        const float inv = rsqrtf(var + 1e-5f);
        float4 o;
        o.x = fmaxf(0.f, (acc[r].x - mu) * inv);
        o.y = fmaxf(0.f, (acc[r].y - mu) * inv);
        o.z = fmaxf(0.f, (acc[r].z - mu) * inv);
        o.w = fmaxf(0.f, (acc[r].w - mu) * inv);
        const int bt = (r & 1) ? bt1 : bt0;
        float* dst = nullptr;
        if (r < 2) dst = ws + XN_OFF + (size_t)bt * NN;
        else if ((bt & 31) > 0) dst = ws + TN_OFF + (size_t)(bt - 1) * NN;
        if (dst) ((float4*)dst)[tid] = o;
    }
}

// ---------------- kernel 2: 4-role persistent pipeline, 4-step batches ----------------
// R5 post-mortem: the batch-4 structure spilled ~19 floats/thread/iter to scratch
// (WRITE_SIZE 62.8MB). This version keeps batch-4 but restores register discipline:
// named scalar u64 gathers (no union arrays -> SROA-safe), no xsave (deferred update
// reloads x from L2-warm xn), v1own as named scalars with compile-time-folded select.
__device__ __forceinline__ float ald(const float* p) {
    return __hip_atomic_load(p, __ATOMIC_RELAXED, __HIP_MEMORY_SCOPE_AGENT);
}
__device__ __forceinline__ unsigned long long ald64(const unsigned long long* p) {
    return __hip_atomic_load(p, __ATOMIC_RELAXED, __HIP_MEMORY_SCOPE_AGENT);
}
__device__ __forceinline__ void ast(float* p, float v) {
    __hip_atomic_store(p, v, __ATOMIC_RELAXED, __HIP_MEMORY_SCOPE_AGENT);
}
__device__ __forceinline__ unsigned aldu_rlx(const unsigned* p) {
    return __hip_atomic_load(p, __ATOMIC_RELAXED, __HIP_MEMORY_SCOPE_AGENT);
}

__global__ __launch_bounds__(512, 1) void mega_kernel(
    const float* __restrict__ Dy, float* __restrict__ out, float* __restrict__ ws)
{
    __shared__ float sh[6144];   // chain: 4 padded p-vectors (1088, stride 1152); out: r[4096]+partial[2048]
    const int blk = blockIdx.x;  // 0..223  (grid <= 256 CUs -> 1 WG/CU, so (512,1) costs no occupancy)
    const int tid = threadIdx.x;

    float* pb     = ws + PB_OFF;
    float* rb     = ws + RB_OFF;
    unsigned* flg = (unsigned*)(ws + FLG_OFF);

    if (blk < 192) {
        // ---- chain stages 0,1,2 ----
        const int stage = blk >> 6;          // 0,1,2
        const int b     = (blk >> 4) & 3;
        const int wg    = blk & 15;
        const int lane  = tid & 63;
        const int w     = tid >> 6;
        const int colbase = wg * 64 + w * 8;   // wave owns cols colbase..+7
        const int row0    = lane * 16;         // lane owns rows row0..+15
        const float* xn = ws + XN_OFF + (size_t)b * TT * NN;
        const float* tn = ws + TN_OFF + (size_t)b * TT * NN;
        unsigned* myflag = flg + ((size_t)(stage * 4 + b) * 16 + wg) * 32;
        const unsigned* inflags =
            (stage > 0) ? flg + ((size_t)((stage - 1) * 4 + b) * 16) * 32 : (const unsigned*)0;
        unsigned seen = 0;   // monotone cache of min producer flag seen by this lane

        float G[16][8];
#pragma unroll
        for (int i = 0; i < 16; ++i)
#pragma unroll
            for (int c = 0; c < 8; ++c)
                G[i][c] = (row0 + i == colbase + c) ? 0.01f : 0.0f;

#pragma unroll 1
        for (int t = 0; t < TT; t += 4) {
            const int bt = b * TT + t;
            float* pbase = pb + (size_t)bt * 2 * NN;   // p1(t+j) = pbase + (2j)*NN, p2(t+j) = +NN

            float v1a = 0.f, v1b = 0.f, v1c = 0.f, v1d = 0.f;

            if (stage != 0) {
                // one RELAXED poll covers all 4 steps: all producers at flag >= t+4
                const unsigned tgt = (unsigned)(t + 4);
                if (tid < 64) {
                    if (seen < tgt) {
                        const unsigned* p = inflags + (size_t)(tid & 15) * 32;
                        int g = 0;
                        for (;;) {
                            unsigned v = aldu_rlx(p);
                            if (v > seen) seen = v;
                            if (__all(seen >= tgt)) break;
                            __builtin_amdgcn_s_sleep(1);
                            if (++g > (1 << 22)) break;  // fail visibly, never hang
                        }
                    }
                }
                __syncthreads();
                asm volatile("" ::: "memory");   // no hoisting of data reads above the poll
                // stage-2 p1 reads for all 4 steps: in flight with the exchange gathers
                if (stage == 2) {
                    const int co8 = colbase + (lane & 7);
                    v1a = ald(pbase + (size_t)0 * NN + co8);
                    v1b = ald(pbase + (size_t)2 * NN + co8);
                    v1c = ald(pbase + (size_t)4 * NN + co8);
                    v1d = ald(pbase + (size_t)6 * NN + co8);
                }
                // cooperative exchange of all 4 vectors: named scalars, one latency window
                const size_t soff = (stage == 1) ? 0 : NN;
                const unsigned long long* s0 =
                    (const unsigned long long*)(pbase + (size_t)0 * NN + soff);
                const unsigned long long* s1 =
                    (const unsigned long long*)(pbase + (size_t)2 * NN + soff);
                const unsigned long long* s2 =
                    (const unsigned long long*)(pbase + (size_t)4 * NN + soff);
                const unsigned long long* s3 =
                    (const unsigned long long*)(pbase + (size_t)6 * NN + soff);
                const unsigned long long g0 = ald64(s0 + tid);
                const unsigned long long g1 = ald64(s1 + tid);
                const unsigned long long g2 = ald64(s2 + tid);
                const unsigned long long g3 = ald64(s3 + tid);
                const int e0 = 2 * tid;
                const int eo = e0 + (e0 >> 4);   // e0 even -> e0 and e0+1 share the pad block
                sh[0 * 1152 + eo]     = __uint_as_float((unsigned)g0);
                sh[0 * 1152 + eo + 1] = __uint_as_float((unsigned)(g0 >> 32));
                sh[1 * 1152 + eo]     = __uint_as_float((unsigned)g1);
                sh[1 * 1152 + eo + 1] = __uint_as_float((unsigned)(g1 >> 32));
                sh[2 * 1152 + eo]     = __uint_as_float((unsigned)g2);
                sh[2 * 1152 + eo + 1] = __uint_as_float((unsigned)(g2 >> 32));
                sh[3 * 1152 + eo]     = __uint_as_float((unsigned)g3);
                sh[3 * 1152 + eo + 1] = __uint_as_float((unsigned)(g3 >> 32));
                __syncthreads();
            }

            // ======== 4 steps: matvec -> store -> G-update (last update deferred) ========
#pragma unroll
            for (int j = 0; j < 4; ++j) {
                const int tj = t + j;
                float in[16];
                if (stage == 0) {
                    const float4* xp = (const float4*)(xn + (size_t)tj * NN + row0);
                    float4 q0 = xp[0], q1 = xp[1], q2 = xp[2], q3 = xp[3];
                    in[0]=q0.x; in[1]=q0.y; in[2]=q0.z; in[3]=q0.w;
                    in[4]=q1.x; in[5]=q1.y; in[6]=q1.z; in[7]=q1.w;
                    in[8]=q2.x; in[9]=q2.y; in[10]=q2.z; in[11]=q2.w;
                    in[12]=q3.x; in[13]=q3.y; in[14]=q3.z; in[15]=q3.w;
                } else {
#pragma unroll
                    for (int k = 0; k < 16; ++k) in[k] = sh[j * 1152 + lane * 17 + k];
                }

                float acc[8] = {0.f,0.f,0.f,0.f,0.f,0.f,0.f,0.f};
#pragma unroll
                for (int i = 0; i < 16; ++i)
#pragma unroll
                    for (int c = 0; c < 8; ++c) acc[c] += in[i] * G[i][c];

                // reduce-scatter: lane ends with full sum for col colbase + (lane&7)
                float t4[8];
#pragma unroll
                for (int c = 0; c < 8; ++c) t4[c] = __shfl_xor(acc[c], 4, 64);
                const bool k2 = (lane & 4) != 0;
                float s4[4];
#pragma unroll
                for (int k = 0; k < 4; ++k) s4[k] = k2 ? (acc[4+k] + t4[4+k]) : (acc[k] + t4[k]);
                float t2[4];
#pragma unroll
                for (int k = 0; k < 4; ++k) t2[k] = __shfl_xor(s4[k], 2, 64);
                const bool k1 = (lane & 2) != 0;
                float s2[2];
#pragma unroll
                for (int k = 0; k < 2; ++k) s2[k] = k1 ? (s4[2+k] + t2[2+k]) : (s4[k] + t2[k]);
                float t1[2];
#pragma unroll
                for (int k = 0; k < 2; ++k) t1[k] = __shfl_xor(s2[k], 1, 64);
                float v = (lane & 1) ? (s2[1] + t1[1]) : (s2[0] + t1[0]);
                v += __shfl_xor(v, 8, 64);
                v += __shfl_xor(v, 16, 64);
                v += __shfl_xor(v, 32, 64);

                if (stage == 0) {
                    if (lane < 8) ast(pbase + (size_t)(2 * j) * NN + colbase + lane, v);
                } else if (stage == 1) {
                    if (lane < 8) ast(pbase + (size_t)(2 * j) * NN + NN + colbase + lane, v);
                } else {
                    const int c = colbase + (lane & 7);
                    const float v2own = sh[j * 1152 + c + (c >> 4)];
                    const float v1o = (j == 0) ? v1a : (j == 1) ? v1b : (j == 2) ? v1c : v1d;
                    float r = fmaxf(v, fmaxf(v1o, v2own));
                    if (lane < 8) ast(rb + (size_t)(bt + j) * NN + colbase + lane, r);
                }

                // inline G update for steps j=0..2 (j=3 deferred past the release)
                if (j < 3) {
                    float x[16];
                    if (stage == 0) {
#pragma unroll
                        for (int k = 0; k < 16; ++k) x[k] = in[k];
                    } else {
                        const float4* xp = (const float4*)(xn + (size_t)tj * NN + row0);
                        float4 q0 = xp[0], q1 = xp[1], q2 = xp[2], q3 = xp[3];
                        x[0]=q0.x; x[1]=q0.y; x[2]=q0.z; x[3]=q0.w;
                        x[4]=q1.x; x[5]=q1.y; x[6]=q1.z; x[7]=q1.w;
                        x[8]=q2.x; x[9]=q2.y; x[10]=q2.z; x[11]=q2.w;
                        x[12]=q3.x; x[13]=q3.y; x[14]=q3.z; x[15]=q3.w;
                    }
                    const float4 ta = *(const float4*)(tn + (size_t)tj * NN + colbase);
                    const float4 tb = *(const float4*)(tn + (size_t)tj * NN + colbase + 4);
                    const float tv[8] = {0.5f*ta.x, 0.5f*ta.y, 0.5f*ta.z, 0.5f*ta.w,
                                         0.5f*tb.x, 0.5f*tb.y, 0.5f*tb.z, 0.5f*tb.w};
#pragma unroll
                    for (int c = 0; c < 8; ++c)
#pragma unroll
                        for (int i = 0; i < 16; ++i)
                            G[i][c] = fmaxf(G[i][c], x[i] * tv[c]);
                }
            }

            __syncthreads();   // one drain for all 4 steps' device-scope stores
            if (tid == 0)      // one RELEASE per batch: publishes steps t..t+3
                __hip_atomic_store(myflag, (unsigned)(t + 4),
                                   __ATOMIC_RELEASE, __HIP_MEMORY_SCOPE_AGENT);

            // deferred G update for step t+3 — after the release, overlaps flag propagation.
            // x reloaded from xn for ALL stages (L2-warm) -> no long-lived xsave registers.
            if (t + 3 < TT - 1) {
                const int tj = t + 3;
                const float4* xp = (const float4*)(xn + (size_t)tj * NN + row0);
                float4 q0 = xp[0], q1 = xp[1], q2 = xp[2], q3 = xp[3];
                float x[16];
                x[0]=q0.x; x[1]=q0.y; x[2]=q0.z; x[3]=q0.w;
                x[4]=q1.x; x[5]=q1.y; x[6]=q1.z; x[7]=q1.w;
                x[8]=q2.x; x[9]=q2.y; x[10]=q2.z; x[11]=q2.w;
                x[12]=q3.x; x[13]=q3.y; x[14]=q3.z; x[15]=q3.w;
                const float4 ta = *(const float4*)(tn + (size_t)tj * NN + colbase);
                const float4 tb = *(const float4*)(tn + (size_t)tj * NN + colbase + 4);
                const float tv[8] = {0.5f*ta.x, 0.5f*ta.y, 0.5f*ta.z, 0.5f*ta.w,
                                     0.5f*tb.x, 0.5f*tb.y, 0.5f*tb.z, 0.5f*tb.w};
#pragma unroll
                for (int c = 0; c < 8; ++c)
#pragma unroll
                    for (int i = 0; i < 16; ++i)
                        G[i][c] = fmaxf(G[i][c], x[i] * tv[c]);
            }
        }
    } else {
        // ---- out stage: y = relu(r @ Dy) for 4 consecutive steps, single Dy pass ----
        const int k   = blk - 192;        // 0..31
        const int b   = k >> 3;
        const int t0  = (k & 7) * 4;
        const int bt0 = b * TT + t0;
        // RELAXED poll of the 16 stage-2 flags (monotone batch counts; t0+4 is a batch boundary)
        if (tid < 64) {
            const unsigned* p = flg + ((size_t)(2 * 4 + b) * 16 + (tid & 15)) * 32;
            const unsigned tgt = (unsigned)(t0 + 4);
            int g = 0;
            for (;;) {
                unsigned v = aldu_rlx(p);
                if (__all(v >= tgt)) break;
                __builtin_amdgcn_s_sleep(1);
                if (++g > (1 << 22)) break;
            }
        }
        __syncthreads();
        asm volatile("" ::: "memory");
#pragma unroll
        for (int j = 0; j < 4; ++j) {
            const float* r = rb + (size_t)(bt0 + j) * NN;
            sh[tid * 4 + j]         = ald(r + tid);
            sh[(tid + 512) * 4 + j] = ald(r + tid + 512);
        }
        __syncthreads();
        const int d = tid & 255, h = tid >> 8;
        float acc[4] = {0.f, 0.f, 0.f, 0.f};
        const int n0 = h * 512;
#pragma unroll 8
        for (int n = n0; n < n0 + 512; ++n) {
            const float dv = Dy[(size_t)n * DD + d];
            const float4 rv = *(const float4*)&sh[n * 4];   // wave-uniform n -> LDS broadcast
            acc[0] += rv.x * dv; acc[1] += rv.y * dv;
            acc[2] += rv.z * dv; acc[3] += rv.w * dv;
        }
#pragma unroll
        for (int j = 0; j < 4; ++j) sh[4096 + (h * 4 + j) * 256 + d] = acc[j];
        __syncthreads();
        if (tid < 256) {
#pragma unroll
            for (int j = 0; j < 4; ++j)
                out[(size_t)(bt0 + j) * DD + tid] =
                    fmaxf(0.f, sh[4096 + j * 256 + tid] + sh[4096 + (4 + j) * 256 + tid]);
        }
    }
}

extern "C" void kernel_launch(void* const* d_in, const int* in_sizes, int n_in,
                              void* d_out, int out_size, void* d_ws, size_t ws_size,
                              hipStream_t stream) {
    const float* x_seq   = (const float*)d_in[0];
    const float* targets = (const float*)d_in[1];
    const float* E       = (const float*)d_in[2];
    const float* Dy      = (const float*)d_in[3];
    float* out = (float*)d_out;
    float* ws  = (float*)d_ws;

    // zero the flags (data is flag-protected; flags are monotone batch counts)
    hipMemsetAsync(ws + FLG_OFF, 0, (size_t)FLG_WORDS * sizeof(unsigned), stream);

    precompute_kernel<<<BB * TT / 2, 256, 0, stream>>>(x_seq, targets, E, ws);
    mega_kernel<<<224, 512, 0, stream>>>(Dy, out, ws);
}